// Round 10
// baseline (260.659 us; speedup 1.0000x reference)
//
#include <hip/hip_runtime.h>
#include <hip/hip_fp16.h>

typedef _Float16 f16;
typedef _Float16 f16x4 __attribute__((ext_vector_type(4)));
typedef _Float16 f16x8 __attribute__((ext_vector_type(8)));
typedef __fp16 h16x2 __attribute__((ext_vector_type(2)));
typedef float f32x4 __attribute__((ext_vector_type(4)));

#define NCH 64          // chunks of 32 rows per batch
#define CHB 32768       // bytes per chunk (32 rows x 256 f32)
#define PSTRIDE 524288  // psc plane stride (floats) = 256*2048

#define BAR()     asm volatile("s_waitcnt lgkmcnt(0)\n\ts_barrier" ::: "memory")
#define WAITV_(N) asm volatile("s_waitcnt vmcnt(" #N ")" ::: "memory")
#define WAITV(N)  WAITV_(N)

// ---------------------------------------------------------------------------
// prep_w: W[0][d][k] (k<256, feature half) -> fp16 HI plane, MFMA B-frag order
// [ks(8)][ct(16)][lane(64)][j(8)]: ct=d>>4, lane=(d&15)|(((k>>3)&3)<<4),
// ks=k>>5, j=k&7. Frag (ks,ct) = contiguous 1 KiB.
// ---------------------------------------------------------------------------
__global__ void prep_w(const float* __restrict__ W, f16* __restrict__ wbuf) {
    int idx = blockIdx.x * 256 + threadIdx.x;   // 65536 total
    int d = idx >> 8, k = idx & 255;
    float w = W[d * 512 + k];
    int ct   = d >> 4;
    int lane = (d & 15) | (((k >> 3) & 3) << 4);
    int ks   = k >> 5;
    int j    = k & 7;
    wbuf[(((ks * 16 + ct) * 64) + lane) * 8 + j] = (f16)w;
}

// ---------------------------------------------------------------------------
// prep_c: c[b][d] = sum_e W[0][d][256+e] * h[b][e]   (fp32 exact, tiny)
// ---------------------------------------------------------------------------
__global__ void prep_c(const float* __restrict__ W, const float* __restrict__ h,
                       float* __restrict__ c) {
    __shared__ float hs[256];
    int b = blockIdx.x, d = threadIdx.x;
    hs[d] = h[b * 256 + d];
    __syncthreads();
    const float4* w4 = (const float4*)(W + d * 512 + 256);
    const float4* h4 = (const float4*)hs;
    float acc = 0.f;
#pragma unroll 8
    for (int e = 0; e < 64; ++e) {
        float4 a = w4[e], bb = h4[e];
        acc += a.x * bb.x + a.y * bb.y + a.z * bb.z + a.w * bb.w;
    }
    c[b * 256 + d] = acc;
}

// ---------------------------------------------------------------------------
// main_gemm: 4-phase interleaved schedule (T3+T4+T5 port of the 8-phase
// template). Per chunk t (32 rows), phase p in 0..3:
//   {ds_read 4 A-frags (ks=2p,2p+1)} {DMA round p of t+2} {vmcnt(4): retires
//   round p of t+1} {cvt round p of t+1} s_barrier {setprio1, 16 MFMA,
//   setprio0} s_barrier.  vmcnt never 0 in steady state; tails peel 3/2/1/0.
// raw ring 2x32K (linear DMA), planes 2x32K f16 hi+lo XOR-swizzled.
// 8 waves = 2 row-halves x 4 col-groups; wave = 16 rows x 64 cols.
// ---------------------------------------------------------------------------
__global__ __launch_bounds__(512, 2)
void main_gemm(const float* __restrict__ feat, const f16* __restrict__ wbuf,
               const float* __restrict__ cb, const float* __restrict__ vvec,
               float* __restrict__ psc) {
    __shared__ __align__(16) char rawb[2 * CHB];    // 64 KiB fp32 ring
    __shared__ __align__(16) char plnb[2 * CHB];    // 64 KiB f16 hi+lo planes

    const int tid = threadIdx.x;
    const int w = tid >> 6;       // wave 0..7
    const int l = tid & 63;
    const int g = l >> 4;         // 0..3
    const int lr = l & 15;
    const int rh = w >> 2;        // row-half 0/1
    const int cg = w & 3;         // col-group 0..3 (64 cols each)
    const int b = blockIdx.x;     // batch

    // ---- W-hi fragments for this wave's 64 cols: wf[ct][ks], 128 VGPRs ----
    f16x8 wf[4][8];
    {
        const f16x8* wp = (const f16x8*)wbuf;
#pragma unroll
        for (int ct = 0; ct < 4; ++ct) {
            int ctg = cg * 4 + ct;
#pragma unroll
            for (int ks = 0; ks < 8; ++ks)
                wf[ct][ks] = wp[(ks * 16 + ctg) * 64 + l];
        }
    }
    float c_[4], v_[4];
#pragma unroll
    for (int ct = 0; ct < 4; ++ct) {
        c_[ct] = cb[b * 256 + (cg * 4 + ct) * 16 + lr];
        v_[ct] = vvec[(cg * 4 + ct) * 16 + lr];
    }

    const char* tbb = (const char*)(feat + (size_t)b * 2048 * 256);

#define ISSUE1(u, i)                                                               \
    {                                                                              \
        const char* nb = tbb + (size_t)(u) * CHB;                                  \
        char* Q = rawb + ((u) & 1) * CHB;                                          \
        __builtin_amdgcn_global_load_lds(                                          \
            (const __attribute__((address_space(1))) void*)(nb + (i) * 8192 + tid * 16), \
            (__attribute__((address_space(3))) void*)(Q + (i) * 8192 + tid * 16),  \
            16, 0, 0);                                                             \
    }

    // cvt round r: flat elems r*2048 + tid*4 -> row r*8+w, k0=(tid&63)*4
    const int ck0 = (tid & 63) * 4;
    int cvt_off[4];
#pragma unroll
    for (int r = 0; r < 4; ++r) {
        int row = r * 8 + w;
        cvt_off[r] = (((row * 512 + (ck0 & ~7) * 2) ^ ((row & 7) << 4)) +
                      ((ck0 & 4) << 1));
    }

#define CVT1(u, r)                                                                 \
    {                                                                              \
        const char* rp = rawb + ((u) & 1) * CHB;                                   \
        char* hq = plnb + ((u) & 1) * CHB;                                         \
        f32x4 x = *(const f32x4*)(rp + (r) * 8192 + tid * 16);                     \
        h16x2 h01 = __builtin_amdgcn_cvt_pkrtz(x[0], x[1]);                        \
        h16x2 h23 = __builtin_amdgcn_cvt_pkrtz(x[2], x[3]);                        \
        h16x2 l01 = __builtin_amdgcn_cvt_pkrtz(x[0] - (float)h01[0],               \
                                               x[1] - (float)h01[1]);              \
        h16x2 l23 = __builtin_amdgcn_cvt_pkrtz(x[2] - (float)h23[0],               \
                                               x[3] - (float)h23[1]);              \
        f16x4 hv = {(f16)(float)h01[0], (f16)(float)h01[1],                        \
                    (f16)(float)h23[0], (f16)(float)h23[1]};                       \
        f16x4 lv = {(f16)(float)l01[0], (f16)(float)l01[1],                        \
                    (f16)(float)l23[0], (f16)(float)l23[1]};                       \
        *(f16x4*)(hq + cvt_off[r]) = hv;                                           \
        *(f16x4*)(hq + 16384 + cvt_off[r]) = lv;                                   \
    }

    // MFMA-phase A addressing (constant per lane): row = rh*16+lr
    const int arow = rh * 16 + lr;
    const int aswz = (arow & 7) << 4;

#define PHASE(P, T, WS, DOISS, DOCVT)                                              \
    {                                                                              \
        const char* hp = plnb + ((T) & 1) * CHB;                                   \
        int ao0 = (arow * 512 + (2 * (P)) * 64 + g * 16) ^ aswz;                   \
        int ao1 = (arow * 512 + (2 * (P) + 1) * 64 + g * 16) ^ aswz;               \
        f16x8 ah0 = *(const f16x8*)(hp + ao0);                                     \
        f16x8 al0 = *(const f16x8*)(hp + 16384 + ao0);                             \
        f16x8 ah1 = *(const f16x8*)(hp + ao1);                                     \
        f16x8 al1 = *(const f16x8*)(hp + 16384 + ao1);                             \
        if (DOISS) ISSUE1((T) + 2, P);                                             \
        WS;                                                                        \
        if (DOCVT) CVT1((T) + 1, P);                                               \
        __builtin_amdgcn_s_barrier();                                              \
        __builtin_amdgcn_s_setprio(1);                                             \
        acc[0] = __builtin_amdgcn_mfma_f32_16x16x32_f16(ah0, wf[0][2*(P)], acc[0], 0, 0, 0); \
        acc[1] = __builtin_amdgcn_mfma_f32_16x16x32_f16(ah0, wf[1][2*(P)], acc[1], 0, 0, 0); \
        acc[2] = __builtin_amdgcn_mfma_f32_16x16x32_f16(ah0, wf[2][2*(P)], acc[2], 0, 0, 0); \
        acc[3] = __builtin_amdgcn_mfma_f32_16x16x32_f16(ah0, wf[3][2*(P)], acc[3], 0, 0, 0); \
        acc[0] = __builtin_amdgcn_mfma_f32_16x16x32_f16(al0, wf[0][2*(P)], acc[0], 0, 0, 0); \
        acc[1] = __builtin_amdgcn_mfma_f32_16x16x32_f16(al0, wf[1][2*(P)], acc[1], 0, 0, 0); \
        acc[2] = __builtin_amdgcn_mfma_f32_16x16x32_f16(al0, wf[2][2*(P)], acc[2], 0, 0, 0); \
        acc[3] = __builtin_amdgcn_mfma_f32_16x16x32_f16(al0, wf[3][2*(P)], acc[3], 0, 0, 0); \
        acc[0] = __builtin_amdgcn_mfma_f32_16x16x32_f16(ah1, wf[0][2*(P)+1], acc[0], 0, 0, 0); \
        acc[1] = __builtin_amdgcn_mfma_f32_16x16x32_f16(ah1, wf[1][2*(P)+1], acc[1], 0, 0, 0); \
        acc[2] = __builtin_amdgcn_mfma_f32_16x16x32_f16(ah1, wf[2][2*(P)+1], acc[2], 0, 0, 0); \
        acc[3] = __builtin_amdgcn_mfma_f32_16x16x32_f16(ah1, wf[3][2*(P)+1], acc[3], 0, 0, 0); \
        acc[0] = __builtin_amdgcn_mfma_f32_16x16x32_f16(al1, wf[0][2*(P)+1], acc[0], 0, 0, 0); \
        acc[1] = __builtin_amdgcn_mfma_f32_16x16x32_f16(al1, wf[1][2*(P)+1], acc[1], 0, 0, 0); \
        acc[2] = __builtin_amdgcn_mfma_f32_16x16x32_f16(al1, wf[2][2*(P)+1], acc[2], 0, 0, 0); \
        acc[3] = __builtin_amdgcn_mfma_f32_16x16x32_f16(al1, wf[3][2*(P)+1], acc[3], 0, 0, 0); \
        __builtin_amdgcn_s_setprio(0);                                             \
        __builtin_amdgcn_s_barrier();                                              \
    }

#define EPI(T)                                                                     \
    {                                                                              \
        float s[4];                                                                \
        _Pragma("unroll")                                                          \
        for (int r = 0; r < 4; ++r) {                                              \
            float a = 0.f;                                                         \
            _Pragma("unroll")                                                      \
            for (int ct = 0; ct < 4; ++ct) {                                       \
                float x = acc[ct][r] + c_[ct];                                     \
                float tnh = 1.f - __fdividef(2.f, __expf(2.f * x) + 1.f);          \
                a += v_[ct] * tnh;                                                 \
            }                                                                      \
            s[r] = a;                                                              \
        }                                                                          \
        _Pragma("unroll")                                                          \
        for (int m = 1; m < 16; m <<= 1) {                                         \
            s[0] += __shfl_xor(s[0], m, 64);                                       \
            s[1] += __shfl_xor(s[1], m, 64);                                       \
            s[2] += __shfl_xor(s[2], m, 64);                                       \
            s[3] += __shfl_xor(s[3], m, 64);                                       \
        }                                                                          \
        if (lr == 0) {                                                             \
            size_t rowg = (size_t)b * 2048 + (T) * 32 + rh * 16 + g * 4;           \
            float4 o = {s[0], s[1], s[2], s[3]};                                   \
            *(float4*)(psc + (size_t)cg * PSTRIDE + rowg) = o;                     \
        }                                                                          \
        BAR();                                                                     \
    }

    // ---- prologue: DMA chunks 0,1; cvt chunk 0 ----
#pragma unroll
    for (int i = 0; i < 4; ++i) ISSUE1(0, i);
#pragma unroll
    for (int i = 0; i < 4; ++i) ISSUE1(1, i);
    WAITV(4);
#pragma unroll
    for (int r = 0; r < 4; ++r) CVT1(0, r);
    BAR();

    // ---- steady chunks 0..61 ----
    for (int t = 0; t < NCH - 2; ++t) {
        f32x4 acc[4] = {};
        PHASE(0, t, WAITV(4), 1, 1)
        PHASE(1, t, WAITV(4), 1, 1)
        PHASE(2, t, WAITV(4), 1, 1)
        PHASE(3, t, WAITV(4), 1, 1)
        EPI(t)
    }
    // ---- chunk 62: no new DMA; peel waits 3/2/1/0 ----
    {
        const int t = NCH - 2;
        f32x4 acc[4] = {};
        PHASE(0, t, WAITV(3), 0, 1)
        PHASE(1, t, WAITV(2), 0, 1)
        PHASE(2, t, WAITV(1), 0, 1)
        PHASE(3, t, WAITV(0), 0, 1)
        EPI(t)
    }
    // ---- chunk 63: pure compute ----
    {
        const int t = NCH - 1;
        f32x4 acc[4] = {};
        PHASE(0, t, ((void)0), 0, 0)
        PHASE(1, t, ((void)0), 0, 0)
        PHASE(2, t, ((void)0), 0, 0)
        PHASE(3, t, ((void)0), 0, 0)
        EPI(t)
    }
#undef ISSUE1
#undef CVT1
#undef PHASE
#undef EPI
}

// ---------------------------------------------------------------------------
// softmax over n (2048) per b, summing 4 plane partials per row.
// ---------------------------------------------------------------------------
__global__ void softmax_k(const float* __restrict__ psc, float* __restrict__ out) {
    __shared__ float red[16];
    int b = blockIdx.x, tid = threadIdx.x;  // 256 threads
    float sc[8];
    float m = -3.4e38f;
#pragma unroll
    for (int q = 0; q < 8; ++q) {
        size_t row = (size_t)b * 2048 + q * 256 + tid;
        sc[q] = (psc[row] + psc[PSTRIDE + row]) +
                (psc[2 * PSTRIDE + row] + psc[3 * PSTRIDE + row]);
        m = fmaxf(m, sc[q]);
    }
#pragma unroll
    for (int d = 1; d < 64; d <<= 1) m = fmaxf(m, __shfl_xor(m, d, 64));
    if ((tid & 63) == 0) red[tid >> 6] = m;
    __syncthreads();
    m = fmaxf(fmaxf(red[0], red[1]), fmaxf(red[2], red[3]));
    float e[8], sum = 0.f;
#pragma unroll
    for (int q = 0; q < 8; ++q) { e[q] = __expf(sc[q] - m); sum += e[q]; }
#pragma unroll
    for (int d = 1; d < 64; d <<= 1) sum += __shfl_xor(sum, d, 64);
    if ((tid & 63) == 0) red[8 + (tid >> 6)] = sum;
    __syncthreads();
    sum = (red[8] + red[9]) + (red[10] + red[11]);
    float inv = __fdividef(1.f, sum);
#pragma unroll
    for (int q = 0; q < 8; ++q)
        out[(size_t)b * 2048 + q * 256 + tid] = e[q] * inv;
}

// ---------------------------------------------------------------------------
extern "C" void kernel_launch(void* const* d_in, const int* in_sizes, int n_in,
                              void* d_out, int out_size, void* d_ws, size_t ws_size,
                              hipStream_t stream) {
    const float* feat = (const float*)d_in[0];   // [256,2048,256]
    const float* h    = (const float*)d_in[1];   // [256,256]
    const float* v    = (const float*)d_in[2];   // [256]
    const float* W    = (const float*)d_in[3];   // [256,512]
    float* out = (float*)d_out;                  // [256,1,2048]

    f16*   wbuf = (f16*)d_ws;                         // 131072 B (hi plane)
    float* cbuf = (float*)((char*)d_ws + 131072);     // 262144 B
    float* psc  = (float*)((char*)d_ws + 524288);     // 4 planes x 2 MiB

    prep_w<<<256, 256, 0, stream>>>(W, wbuf);
    prep_c<<<256, 256, 0, stream>>>(W, h, cbuf);
    main_gemm<<<256, 512, 0, stream>>>(feat, wbuf, cbuf, v, psc);
    softmax_k<<<256, 256, 0, stream>>>(psc, out);
}

// Round 11
// 214.910 us; speedup vs baseline: 1.2129x; 1.2129x over previous
//
#include <hip/hip_runtime.h>
#include <hip/hip_fp16.h>

typedef _Float16 f16;
typedef _Float16 f16x4 __attribute__((ext_vector_type(4)));
typedef _Float16 f16x8 __attribute__((ext_vector_type(8)));
typedef __fp16 h16x2 __attribute__((ext_vector_type(2)));
typedef float f32x4 __attribute__((ext_vector_type(4)));

#define NCH 64          // chunks of 16 rows per block (block = half batch)
#define CHB 16384       // bytes per chunk (16 rows x 256 f32)
#define PSTRIDE 524288  // psc plane stride (floats) = 256*2048

#define BAR()     asm volatile("s_waitcnt lgkmcnt(0)\n\ts_barrier" ::: "memory")
#define WAITV_(N) asm volatile("s_waitcnt vmcnt(" #N ")" ::: "memory")
#define WAITV(N)  WAITV_(N)

// ---------------------------------------------------------------------------
// prep_w: W[0][d][k] (k<256, feature half) -> fp16 HI plane, MFMA B-frag order
// [ks(8)][ct(16)][lane(64)][j(8)]: ct=d>>4, lane=(d&15)|(((k>>3)&3)<<4),
// ks=k>>5, j=k&7. Frag (ks,ct) = contiguous 1 KiB.
// ---------------------------------------------------------------------------
__global__ void prep_w(const float* __restrict__ W, f16* __restrict__ wbuf) {
    int idx = blockIdx.x * 256 + threadIdx.x;   // 65536 total
    int d = idx >> 8, k = idx & 255;
    float w = W[d * 512 + k];
    int ct   = d >> 4;
    int lane = (d & 15) | (((k >> 3) & 3) << 4);
    int ks   = k >> 5;
    int j    = k & 7;
    wbuf[(((ks * 16 + ct) * 64) + lane) * 8 + j] = (f16)w;
}

// ---------------------------------------------------------------------------
// prep_c: c[b][d] = sum_e W[0][d][256+e] * h[b][e]   (fp32 exact, tiny)
// ---------------------------------------------------------------------------
__global__ void prep_c(const float* __restrict__ W, const float* __restrict__ h,
                       float* __restrict__ c) {
    __shared__ float hs[256];
    int b = blockIdx.x, d = threadIdx.x;
    hs[d] = h[b * 256 + d];
    __syncthreads();
    const float4* w4 = (const float4*)(W + d * 512 + 256);
    const float4* h4 = (const float4*)hs;
    float acc = 0.f;
#pragma unroll 8
    for (int e = 0; e < 64; ++e) {
        float4 a = w4[e], bb = h4[e];
        acc += a.x * bb.x + a.y * bb.y + a.z * bb.z + a.w * bb.w;
    }
    c[b * 256 + d] = acc;
}

// ---------------------------------------------------------------------------
// main_gemm: TWO INDEPENDENT BLOCKS PER CU (separate barrier domains hide
// each other's barrier/epilogue/wait stalls). 512 blocks x 256 threads;
// block j = batch j>>1, row-half j&1 (1024 rows = 64 chunks of 16).
// Per-block LDS: raw ring 2x16K (linear fp32, DMA) + planes 2x16K (f16 hi/lo,
// XOR-swizzled) = 64 KB -> exactly 2 blocks/CU.
// Pipeline per chunk t (identical to R9): BAR -> ISSUE(t+2) -> MFMA planes[t]
// -> epilogue -> WAITV(4) -> CVT(t+1) -> psc store. vmcnt never 0 in steady.
// 4 waves = 4 col-groups; wave = 16 rows x 64 cols; wf[4][8]=128 VGPR.
// ---------------------------------------------------------------------------
__global__ __launch_bounds__(256, 2)
void main_gemm(const float* __restrict__ feat, const f16* __restrict__ wbuf,
               const float* __restrict__ cb, const float* __restrict__ vvec,
               float* __restrict__ psc) {
    __shared__ __align__(16) char rawb[2 * CHB];    // 32 KiB fp32 ring
    __shared__ __align__(16) char plnb[2 * CHB];    // 32 KiB f16 hi+lo planes

    const int tid = threadIdx.x;
    const int w = tid >> 6;       // wave 0..3 == col-group (64 cols each)
    const int l = tid & 63;
    const int g = l >> 4;         // 0..3
    const int lr = l & 15;
    const int b = blockIdx.x >> 1;      // batch
    const int half = blockIdx.x & 1;    // row-half of the batch

    // ---- W-hi fragments for this wave's 64 cols: wf[ct][ks], 128 VGPRs ----
    f16x8 wf[4][8];
    {
        const f16x8* wp = (const f16x8*)wbuf;
#pragma unroll
        for (int ct = 0; ct < 4; ++ct) {
            int ctg = w * 4 + ct;
#pragma unroll
            for (int ks = 0; ks < 8; ++ks)
                wf[ct][ks] = wp[(ks * 16 + ctg) * 64 + l];
        }
    }
    float c_[4], v_[4];
#pragma unroll
    for (int ct = 0; ct < 4; ++ct) {
        c_[ct] = cb[b * 256 + (w * 4 + ct) * 16 + lr];
        v_[ct] = vvec[(w * 4 + ct) * 16 + lr];
    }

    const char* tbb = (const char*)(feat + ((size_t)b * 2048 + half * 1024) * 256);

    // DMA: 4 rounds x 256 thr x 16 B = 16 KB/chunk, linear both sides.
#define ISSUE(u)                                                                   \
    {                                                                              \
        const char* nb = tbb + (size_t)(u) * CHB;                                  \
        char* Q = rawb + ((u) & 1) * CHB;                                          \
        _Pragma("unroll")                                                          \
        for (int i = 0; i < 4; ++i)                                                \
            __builtin_amdgcn_global_load_lds(                                      \
                (const __attribute__((address_space(1))) void*)(nb + i * 4096 + tid * 16), \
                (__attribute__((address_space(3))) void*)(Q + i * 4096 + tid * 16),\
                16, 0, 0);                                                         \
    }

    // cvt round r: LDS byte x = r*4096 + tid*16 -> row = r*4 + (tid>>6),
    // k0 = (tid&63)*4.  planes: elem(row,k) at (row*512+k*2)^((row&7)<<4).
    const int ck0 = (tid & 63) * 4;
    int cvt_off[4];
#pragma unroll
    for (int r = 0; r < 4; ++r) {
        int row = r * 4 + (tid >> 6);
        cvt_off[r] = (((row * 512 + (ck0 & ~7) * 2) ^ ((row & 7) << 4)) +
                      ((ck0 & 4) << 1));
    }

#define CVT(u)                                                                     \
    {                                                                              \
        const char* rp = rawb + ((u) & 1) * CHB;                                   \
        char* hq = plnb + ((u) & 1) * CHB;                                         \
        _Pragma("unroll")                                                          \
        for (int r = 0; r < 4; ++r) {                                              \
            f32x4 x = *(const f32x4*)(rp + r * 4096 + tid * 16);                   \
            h16x2 h01 = __builtin_amdgcn_cvt_pkrtz(x[0], x[1]);                    \
            h16x2 h23 = __builtin_amdgcn_cvt_pkrtz(x[2], x[3]);                    \
            h16x2 l01 = __builtin_amdgcn_cvt_pkrtz(x[0] - (float)h01[0],           \
                                                   x[1] - (float)h01[1]);          \
            h16x2 l23 = __builtin_amdgcn_cvt_pkrtz(x[2] - (float)h23[0],           \
                                                   x[3] - (float)h23[1]);          \
            f16x4 hv = {(f16)(float)h01[0], (f16)(float)h01[1],                    \
                        (f16)(float)h23[0], (f16)(float)h23[1]};                   \
            f16x4 lv = {(f16)(float)l01[0], (f16)(float)l01[1],                    \
                        (f16)(float)l23[0], (f16)(float)l23[1]};                   \
            *(f16x4*)(hq + cvt_off[r]) = hv;                                       \
            *(f16x4*)(hq + 8192 + cvt_off[r]) = lv;                                \
        }                                                                          \
    }

    // MFMA-phase A addressing (constant per lane): row = lr
    const int aswz = (lr & 7) << 4;

    // ---- prologue: DMA chunks 0,1; cvt chunk 0 ----
    ISSUE(0); ISSUE(1);
    WAITV(4);            // raw[0] complete (raw[1] still flying)
    CVT(0);

    for (int t = 0; t < NCH; ++t) {
        BAR();           // planes[t] visible; raw slot ((t+2)&1)==(t&1) free
        if (t + 2 < NCH) ISSUE(t + 2);

        const char* hp = plnb + (t & 1) * CHB;
        f32x4 acc[4] = {};
#pragma unroll
        for (int ks = 0; ks < 8; ++ks) {
            int ao = (lr * 512 + ks * 64 + g * 16) ^ aswz;
            f16x8 ahi = *(const f16x8*)(hp + ao);
            f16x8 alo = *(const f16x8*)(hp + 8192 + ao);
            acc[0] = __builtin_amdgcn_mfma_f32_16x16x32_f16(ahi, wf[0][ks], acc[0], 0, 0, 0);
            acc[1] = __builtin_amdgcn_mfma_f32_16x16x32_f16(ahi, wf[1][ks], acc[1], 0, 0, 0);
            acc[2] = __builtin_amdgcn_mfma_f32_16x16x32_f16(ahi, wf[2][ks], acc[2], 0, 0, 0);
            acc[3] = __builtin_amdgcn_mfma_f32_16x16x32_f16(ahi, wf[3][ks], acc[3], 0, 0, 0);
            acc[0] = __builtin_amdgcn_mfma_f32_16x16x32_f16(alo, wf[0][ks], acc[0], 0, 0, 0);
            acc[1] = __builtin_amdgcn_mfma_f32_16x16x32_f16(alo, wf[1][ks], acc[1], 0, 0, 0);
            acc[2] = __builtin_amdgcn_mfma_f32_16x16x32_f16(alo, wf[2][ks], acc[2], 0, 0, 0);
            acc[3] = __builtin_amdgcn_mfma_f32_16x16x32_f16(alo, wf[3][ks], acc[3], 0, 0, 0);
        }

        // ---- epilogue compute: +c, tanh, *v, reduce over 64 cols ----
        // acc[ct][r]: row = g*4 + r, col = (w*4+ct)*16 + lr
        float s[4];
#pragma unroll
        for (int r = 0; r < 4; ++r) {
            float a = 0.f;
#pragma unroll
            for (int ct = 0; ct < 4; ++ct) {
                float x = acc[ct][r] + c_[ct];
                float tnh = 1.f - __fdividef(2.f, __expf(2.f * x) + 1.f);
                a += v_[ct] * tnh;
            }
            s[r] = a;
        }
#pragma unroll
        for (int m = 1; m < 16; m <<= 1) {
            s[0] += __shfl_xor(s[0], m, 64);
            s[1] += __shfl_xor(s[1], m, 64);
            s[2] += __shfl_xor(s[2], m, 64);
            s[3] += __shfl_xor(s[3], m, 64);
        }

        // ---- retire raw[t+1], cvt it (raw[t+2] stays in flight) ----
        if (t < NCH - 2)      WAITV(4);
        else if (t == NCH - 2) WAITV(1);   // queue: [63 loads(4), store(1)]
        if (t + 1 < NCH) CVT(t + 1);

        if (lr == 0) {
            size_t rowg = (size_t)b * 2048 + half * 1024 + t * 16 + g * 4;
            float4 o = {s[0], s[1], s[2], s[3]};
            *(float4*)(psc + (size_t)w * PSTRIDE + rowg) = o;
        }
    }
#undef ISSUE
#undef CVT
}

// ---------------------------------------------------------------------------
// softmax over n (2048) per b, summing 4 plane partials per row.
// ---------------------------------------------------------------------------
__global__ void softmax_k(const float* __restrict__ psc, float* __restrict__ out) {
    __shared__ float red[16];
    int b = blockIdx.x, tid = threadIdx.x;  // 256 threads
    float sc[8];
    float m = -3.4e38f;
#pragma unroll
    for (int q = 0; q < 8; ++q) {
        size_t row = (size_t)b * 2048 + q * 256 + tid;
        sc[q] = (psc[row] + psc[PSTRIDE + row]) +
                (psc[2 * PSTRIDE + row] + psc[3 * PSTRIDE + row]);
        m = fmaxf(m, sc[q]);
    }
#pragma unroll
    for (int d = 1; d < 64; d <<= 1) m = fmaxf(m, __shfl_xor(m, d, 64));
    if ((tid & 63) == 0) red[tid >> 6] = m;
    __syncthreads();
    m = fmaxf(fmaxf(red[0], red[1]), fmaxf(red[2], red[3]));
    float e[8], sum = 0.f;
#pragma unroll
    for (int q = 0; q < 8; ++q) { e[q] = __expf(sc[q] - m); sum += e[q]; }
#pragma unroll
    for (int d = 1; d < 64; d <<= 1) sum += __shfl_xor(sum, d, 64);
    if ((tid & 63) == 0) red[8 + (tid >> 6)] = sum;
    __syncthreads();
    sum = (red[8] + red[9]) + (red[10] + red[11]);
    float inv = __fdividef(1.f, sum);
#pragma unroll
    for (int q = 0; q < 8; ++q)
        out[(size_t)b * 2048 + q * 256 + tid] = e[q] * inv;
}

// ---------------------------------------------------------------------------
extern "C" void kernel_launch(void* const* d_in, const int* in_sizes, int n_in,
                              void* d_out, int out_size, void* d_ws, size_t ws_size,
                              hipStream_t stream) {
    const float* feat = (const float*)d_in[0];   // [256,2048,256]
    const float* h    = (const float*)d_in[1];   // [256,256]
    const float* v    = (const float*)d_in[2];   // [256]
    const float* W    = (const float*)d_in[3];   // [256,512]
    float* out = (float*)d_out;                  // [256,1,2048]

    f16*   wbuf = (f16*)d_ws;                         // 131072 B (hi plane)
    float* cbuf = (float*)((char*)d_ws + 131072);     // 262144 B
    float* psc  = (float*)((char*)d_ws + 524288);     // 4 planes x 2 MiB

    prep_w<<<256, 256, 0, stream>>>(W, wbuf);
    prep_c<<<256, 256, 0, stream>>>(W, h, cbuf);
    main_gemm<<<512, 256, 0, stream>>>(feat, wbuf, cbuf, v, psc);
    softmax_k<<<256, 256, 0, stream>>>(psc, out);
}

// Round 12
// 167.673 us; speedup vs baseline: 1.5546x; 1.2817x over previous
//
#include <hip/hip_runtime.h>
#include <hip/hip_fp16.h>

typedef _Float16 f16;
typedef _Float16 f16x4 __attribute__((ext_vector_type(4)));
typedef _Float16 f16x8 __attribute__((ext_vector_type(8)));
typedef float f32x4 __attribute__((ext_vector_type(4)));

#define NCH 64          // chunks of 32 rows per batch
#define CHB 32768       // raw bytes per chunk (32 rows x 256 f32)
#define PLB 16384       // plane bytes per chunk (32 rows x 256 f16)
#define PSTRIDE 524288  // psc plane stride (floats) = 256*2048

#define BAR()     asm volatile("s_waitcnt lgkmcnt(0)\n\ts_barrier" ::: "memory")
#define WAITV_(N) asm volatile("s_waitcnt vmcnt(" #N ")" ::: "memory")
#define WAITV(N)  WAITV_(N)

// ---------------------------------------------------------------------------
// prep_w: W[0][d][k] (k<256, feature half) -> fp16 HI plane (RTN), MFMA B-frag
// order [ks(8)][ct(16)][lane(64)][j(8)]: ct=d>>4, lane=(d&15)|(((k>>3)&3)<<4),
// ks=k>>5, j=k&7. Frag (ks,ct) = contiguous 1 KiB.
// ---------------------------------------------------------------------------
__global__ void prep_w(const float* __restrict__ W, f16* __restrict__ wbuf) {
    int idx = blockIdx.x * 256 + threadIdx.x;   // 65536 total
    int d = idx >> 8, k = idx & 255;
    float w = W[d * 512 + k];
    int ct   = d >> 4;
    int lane = (d & 15) | (((k >> 3) & 3) << 4);
    int ks   = k >> 5;
    int j    = k & 7;
    wbuf[(((ks * 16 + ct) * 64) + lane) * 8 + j] = (f16)w;
}

// ---------------------------------------------------------------------------
// prep_c: c[b][d] = sum_e W[0][d][256+e] * h[b][e]   (fp32 exact, tiny)
// ---------------------------------------------------------------------------
__global__ void prep_c(const float* __restrict__ W, const float* __restrict__ h,
                       float* __restrict__ c) {
    __shared__ float hs[256];
    int b = blockIdx.x, d = threadIdx.x;
    hs[d] = h[b * 256 + d];
    __syncthreads();
    const float4* w4 = (const float4*)(W + d * 512 + 256);
    const float4* h4 = (const float4*)hs;
    float acc = 0.f;
#pragma unroll 8
    for (int e = 0; e < 64; ++e) {
        float4 a = w4[e], bb = h4[e];
        acc += a.x * bb.x + a.y * bb.y + a.z * bb.z + a.w * bb.w;
    }
    c[b * 256 + d] = acc;
}

// ---------------------------------------------------------------------------
// main_gemm: SINGLE-PASS f16 (f_hi*W_hi, RTN conversions; dropped terms
// f_lo*W + f_hi*W_lo each ~2^-12-scale -> absmax ~ sqrt(2) x 2-pass).
// R9 skeleton: raw ring 2x32K (linear fp32 DMA), planes 2x16K f16 hi only,
// XOR-swizzled: elem (row,k) at byte (row*512 + k*2) ^ ((row&7)<<4).
// Per iter t: BAR -> ISSUE(t+2) -> MFMA planes[t] (8 ds_read + 32 MFMA/wave)
// -> epilogue -> WAITV(4) -> CVT(t+1) -> psc store. vmcnt never 0 in steady.
// 8 waves = 2 row-halves x 4 col-groups; wave = 16 rows x 64 cols.
// wf[4][8]=128 VGPR + acc 16 -> ~190 regs, 2 waves/SIMD, no spill.
// ---------------------------------------------------------------------------
__global__ __launch_bounds__(512, 2)
void main_gemm(const float* __restrict__ feat, const f16* __restrict__ wbuf,
               const float* __restrict__ cb, const float* __restrict__ vvec,
               float* __restrict__ psc) {
    __shared__ __align__(16) char rawb[2 * CHB];    // 64 KiB fp32 ring
    __shared__ __align__(16) char plnb[2 * PLB];    // 32 KiB f16 hi planes

    const int tid = threadIdx.x;
    const int w = tid >> 6;       // wave 0..7
    const int l = tid & 63;
    const int g = l >> 4;         // 0..3
    const int lr = l & 15;
    const int rh = w >> 2;        // row-half 0/1
    const int cg = w & 3;         // col-group 0..3 (64 cols each)
    const int b = blockIdx.x;     // batch

    // ---- W-hi fragments for this wave's 64 cols: wf[ct][ks], 128 VGPRs ----
    f16x8 wf[4][8];
    {
        const f16x8* wp = (const f16x8*)wbuf;
#pragma unroll
        for (int ct = 0; ct < 4; ++ct) {
            int ctg = cg * 4 + ct;
#pragma unroll
            for (int ks = 0; ks < 8; ++ks)
                wf[ct][ks] = wp[(ks * 16 + ctg) * 64 + l];
        }
    }
    float c_[4], v_[4];
#pragma unroll
    for (int ct = 0; ct < 4; ++ct) {
        c_[ct] = cb[b * 256 + (cg * 4 + ct) * 16 + lr];
        v_[ct] = vvec[(cg * 4 + ct) * 16 + lr];
    }

    const char* tbb = (const char*)(feat + (size_t)b * 2048 * 256);

    // DMA: 4 rounds x 512 thr x 16 B = 32 KB, fully linear both sides.
#define ISSUE(u)                                                                   \
    {                                                                              \
        const char* nb = tbb + (size_t)(u) * CHB;                                  \
        char* Q = rawb + ((u) & 1) * CHB;                                          \
        _Pragma("unroll")                                                          \
        for (int i = 0; i < 4; ++i)                                                \
            __builtin_amdgcn_global_load_lds(                                      \
                (const __attribute__((address_space(1))) void*)(nb + i * 8192 + tid * 16), \
                (__attribute__((address_space(3))) void*)(Q + i * 8192 + tid * 16),\
                16, 0, 0);                                                         \
    }

    // cvt round r: flat elems r*2048 + tid*4 -> row r*8+w, k0=(tid&63)*4
    const int ck0 = (tid & 63) * 4;
    int cvt_off[4];
#pragma unroll
    for (int r = 0; r < 4; ++r) {
        int row = r * 8 + w;
        cvt_off[r] = (((row * 512 + (ck0 & ~7) * 2) ^ ((row & 7) << 4)) +
                      ((ck0 & 4) << 1));
    }

#define CVT(u)                                                                     \
    {                                                                              \
        const char* rp = rawb + ((u) & 1) * CHB;                                   \
        char* hq = plnb + ((u) & 1) * PLB;                                         \
        _Pragma("unroll")                                                          \
        for (int r = 0; r < 4; ++r) {                                              \
            f32x4 x = *(const f32x4*)(rp + r * 8192 + tid * 16);                   \
            f16x4 hv = {(f16)x[0], (f16)x[1], (f16)x[2], (f16)x[3]};               \
            *(f16x4*)(hq + cvt_off[r]) = hv;                                       \
        }                                                                          \
    }

    // MFMA-phase A addressing (constant per lane): row = rh*16+lr
    const int arow = rh * 16 + lr;
    const int aswz = (arow & 7) << 4;

    // ---- prologue: DMA chunks 0,1; cvt chunk 0 ----
    ISSUE(0); ISSUE(1);
    WAITV(4);            // raw[0] complete (raw[1] still flying)
    CVT(0);

    for (int t = 0; t < NCH; ++t) {
        BAR();           // planes[t] visible; raw slot (t&1) free for DMA
        if (t + 2 < NCH) ISSUE(t + 2);

        const char* hp = plnb + (t & 1) * PLB;
        f32x4 acc[4] = {};
#pragma unroll
        for (int ks = 0; ks < 8; ++ks) {
            int ao = (arow * 512 + ks * 64 + g * 16) ^ aswz;
            f16x8 ahi = *(const f16x8*)(hp + ao);
            acc[0] = __builtin_amdgcn_mfma_f32_16x16x32_f16(ahi, wf[0][ks], acc[0], 0, 0, 0);
            acc[1] = __builtin_amdgcn_mfma_f32_16x16x32_f16(ahi, wf[1][ks], acc[1], 0, 0, 0);
            acc[2] = __builtin_amdgcn_mfma_f32_16x16x32_f16(ahi, wf[2][ks], acc[2], 0, 0, 0);
            acc[3] = __builtin_amdgcn_mfma_f32_16x16x32_f16(ahi, wf[3][ks], acc[3], 0, 0, 0);
        }

        // ---- epilogue compute: +c, tanh, *v, reduce over 64 cols ----
        // acc[ct][r]: row = rh*16 + g*4 + r, col = (cg*4+ct)*16 + lr
        float s[4];
#pragma unroll
        for (int r = 0; r < 4; ++r) {
            float a = 0.f;
#pragma unroll
            for (int ct = 0; ct < 4; ++ct) {
                float x = acc[ct][r] + c_[ct];
                float tnh = 1.f - __fdividef(2.f, __expf(2.f * x) + 1.f);
                a += v_[ct] * tnh;
            }
            s[r] = a;
        }
#pragma unroll
        for (int m = 1; m < 16; m <<= 1) {
            s[0] += __shfl_xor(s[0], m, 64);
            s[1] += __shfl_xor(s[1], m, 64);
            s[2] += __shfl_xor(s[2], m, 64);
            s[3] += __shfl_xor(s[3], m, 64);
        }

        // ---- retire raw[t+1], cvt it (raw[t+2] stays in flight) ----
        if (t < NCH - 2)      WAITV(4);
        else if (t == NCH - 2) WAITV(0);
        if (t + 1 < NCH) CVT(t + 1);

        if (lr == 0) {
            size_t rowg = (size_t)b * 2048 + t * 32 + rh * 16 + g * 4;
            float4 o = {s[0], s[1], s[2], s[3]};
            *(float4*)(psc + (size_t)cg * PSTRIDE + rowg) = o;
        }
    }
#undef ISSUE
#undef CVT
}

// ---------------------------------------------------------------------------
// softmax over n (2048) per b, summing 4 plane partials per row.
// ---------------------------------------------------------------------------
__global__ void softmax_k(const float* __restrict__ psc, float* __restrict__ out) {
    __shared__ float red[16];
    int b = blockIdx.x, tid = threadIdx.x;  // 256 threads
    float sc[8];
    float m = -3.4e38f;
#pragma unroll
    for (int q = 0; q < 8; ++q) {
        size_t row = (size_t)b * 2048 + q * 256 + tid;
        sc[q] = (psc[row] + psc[PSTRIDE + row]) +
                (psc[2 * PSTRIDE + row] + psc[3 * PSTRIDE + row]);
        m = fmaxf(m, sc[q]);
    }
#pragma unroll
    for (int d = 1; d < 64; d <<= 1) m = fmaxf(m, __shfl_xor(m, d, 64));
    if ((tid & 63) == 0) red[tid >> 6] = m;
    __syncthreads();
    m = fmaxf(fmaxf(red[0], red[1]), fmaxf(red[2], red[3]));
    float e[8], sum = 0.f;
#pragma unroll
    for (int q = 0; q < 8; ++q) { e[q] = __expf(sc[q] - m); sum += e[q]; }
#pragma unroll
    for (int d = 1; d < 64; d <<= 1) sum += __shfl_xor(sum, d, 64);
    if ((tid & 63) == 0) red[8 + (tid >> 6)] = sum;
    __syncthreads();
    sum = (red[8] + red[9]) + (red[10] + red[11]);
    float inv = __fdividef(1.f, sum);
#pragma unroll
    for (int q = 0; q < 8; ++q)
        out[(size_t)b * 2048 + q * 256 + tid] = e[q] * inv;
}

// ---------------------------------------------------------------------------
extern "C" void kernel_launch(void* const* d_in, const int* in_sizes, int n_in,
                              void* d_out, int out_size, void* d_ws, size_t ws_size,
                              hipStream_t stream) {
    const float* feat = (const float*)d_in[0];   // [256,2048,256]
    const float* h    = (const float*)d_in[1];   // [256,256]
    const float* v    = (const float*)d_in[2];   // [256]
    const float* W    = (const float*)d_in[3];   // [256,512]
    float* out = (float*)d_out;                  // [256,1,2048]

    f16*   wbuf = (f16*)d_ws;                         // 131072 B (hi plane)
    float* cbuf = (float*)((char*)d_ws + 131072);     // 262144 B
    float* psc  = (float*)((char*)d_ws + 524288);     // 4 planes x 2 MiB

    prep_w<<<256, 256, 0, stream>>>(W, wbuf);
    prep_c<<<256, 256, 0, stream>>>(W, h, cbuf);
    main_gemm<<<256, 512, 0, stream>>>(feat, wbuf, cbuf, v, psc);
    softmax_k<<<256, 256, 0, stream>>>(psc, out);
}